// Round 4
// baseline (8993.827 us; speedup 1.0000x reference)
//
#include <hip/hip_runtime.h>
#include <math.h>

#define B 256
#define L 256
#define H 512
#define H3 1536
#define TOKV 128
#define EOS_TOK 1
#define OUTC 257
#define SLOT ((size_t)B * H)   // floats per h-state

typedef short s16;
typedef s16 s16x8 __attribute__((ext_vector_type(8)));
typedef s16 s16x4 __attribute__((ext_vector_type(4)));
typedef float f32x4v __attribute__((ext_vector_type(4)));

__device__ __forceinline__ float sigmoidf_(float x) {
    return 1.0f / (1.0f + __expf(-x));
}

// fp32 -> bf16 bit pattern, round-to-nearest-even (same as (__bf16) cast)
__device__ __forceinline__ s16 f2bf(float x) {
    unsigned u = __builtin_bit_cast(unsigned, x);
    u += 0x7fffu + ((u >> 16) & 1u);
    return (s16)(u >> 16);
}
__device__ __forceinline__ float bf2f(s16 h) {
    return __builtin_bit_cast(float, ((unsigned)(unsigned short)h) << 16);
}

// ---------------- grid barrier (monotonic, two-level tree) ----------------
// bar layout: group g counter at bar[g*32] (g=0..15), root at bar[512].
// Barrier #n (n>=1): every WG adds 1 to its group; group leader waits for 16*n
// then adds to root; all spin until root >= 16*n. Counters never reset (zeroed
// per kernel_launch via hipMemsetAsync), so replays are deterministic.
__device__ __forceinline__ void gridbar(unsigned* bar, int wg, unsigned n, int tid) {
    __threadfence();            // release our global writes (wb to coherence point)
    __syncthreads();
    if (tid == 0) {
        const unsigned tgt = 16u * n;
        const int grp = wg >> 4;
        __hip_atomic_fetch_add(&bar[grp * 32], 1u, __ATOMIC_RELAXED, __HIP_MEMORY_SCOPE_AGENT);
        if ((wg & 15) == 0) {
            while (__hip_atomic_load(&bar[grp * 32], __ATOMIC_RELAXED,
                                     __HIP_MEMORY_SCOPE_AGENT) < tgt) {}
            __hip_atomic_fetch_add(&bar[512], 1u, __ATOMIC_RELAXED, __HIP_MEMORY_SCOPE_AGENT);
        }
        while (__hip_atomic_load(&bar[512], __ATOMIC_RELAXED,
                                 __HIP_MEMORY_SCOPE_AGENT) < tgt) {
            __builtin_amdgcn_s_sleep(2);
        }
    }
    __syncthreads();
    __threadfence();            // acquire: invalidate stale cached lines
}

// ---------------- prep: elementwise split of a fp32 weight array ----------------
__global__ __launch_bounds__(256) void k_split(const float* __restrict__ src,
                                               s16* __restrict__ hi,
                                               s16* __restrict__ lo, int n4) {
    int i = blockIdx.x * 256 + threadIdx.x;
    if (i >= n4) return;
    float4 x = ((const float4*)src)[i];
    float xs[4] = {x.x, x.y, x.z, x.w};
    s16x4 h, l;
    #pragma unroll
    for (int q = 0; q < 4; ++q) {
        s16 hh = f2bf(xs[q]);
        h[q] = hh;
        l[q] = f2bf(xs[q] - bf2f(hh));
    }
    *(s16x4*)(hi + (size_t)i * 4) = h;
    *(s16x4*)(lo + (size_t)i * 4) = l;
}

// ---------------- prep: gi_tok[v][j] = relu(token_emb[v]) . w_ih[j] + b_ih[j] (fp32) ----------------
__global__ __launch_bounds__(256) void k_gi_tok(
        const float* __restrict__ token_emb, const float* __restrict__ w_ih,
        const float* __restrict__ b_ih, float* __restrict__ gi_out) {
    __shared__ float wlds[96][132];
    __shared__ float elds[16][132];
    const int vi = blockIdx.x >> 4;
    const int ji = blockIdx.x & 15;
    const int v0 = vi << 4, j0 = ji * 96;
    const int tid = threadIdx.x;
    const int vl = tid & 7;
    const int jl = tid >> 3;
    float acc[2][3] = {{0.f, 0.f, 0.f}, {0.f, 0.f, 0.f}};
    for (int ck = 0; ck < 4; ++ck) {
        const int c0 = ck << 7;
        __syncthreads();
        for (int i = tid; i < 96 * 32; i += 256) {
            int row = i >> 5, c4 = i & 31;
            *(float4*)&wlds[row][c4 << 2] =
                *(const float4*)(w_ih + (size_t)(j0 + row) * H + c0 + (c4 << 2));
        }
        for (int i = tid; i < 16 * 32; i += 256) {
            int row = i >> 5, c4 = i & 31;
            float4 e = *(const float4*)(token_emb + (size_t)(v0 + row) * H + c0 + (c4 << 2));
            e.x = fmaxf(e.x, 0.f); e.y = fmaxf(e.y, 0.f);
            e.z = fmaxf(e.z, 0.f); e.w = fmaxf(e.w, 0.f);
            *(float4*)&elds[row][c4 << 2] = e;
        }
        __syncthreads();
        #pragma unroll 8
        for (int c = 0; c < 128; c += 4) {
            float4 wa = *(const float4*)&wlds[jl][c];
            float4 wb = *(const float4*)&wlds[32 + jl][c];
            float4 wc = *(const float4*)&wlds[64 + jl][c];
            float4 ea = *(const float4*)&elds[vl][c];
            float4 eb = *(const float4*)&elds[vl + 8][c];
            acc[0][0] += ea.x*wa.x + ea.y*wa.y + ea.z*wa.z + ea.w*wa.w;
            acc[0][1] += ea.x*wb.x + ea.y*wb.y + ea.z*wb.z + ea.w*wb.w;
            acc[0][2] += ea.x*wc.x + ea.y*wc.y + ea.z*wc.z + ea.w*wc.w;
            acc[1][0] += eb.x*wa.x + eb.y*wa.y + eb.z*wa.z + eb.w*wa.w;
            acc[1][1] += eb.x*wb.x + eb.y*wb.y + eb.z*wb.z + eb.w*wb.w;
            acc[1][2] += eb.x*wc.x + eb.y*wc.y + eb.z*wc.z + eb.w*wc.w;
        }
    }
    #pragma unroll
    for (int p = 0; p < 2; ++p) {
        int v = v0 + vl + (p << 3);
        #pragma unroll
        for (int s = 0; s < 3; ++s) {
            int j = j0 + (s << 5) + jl;
            gi_out[(size_t)v * H3 + j] = acc[p][s] + b_ih[j];
        }
    }
}

// ---------------- persistent GRU scan (cooperative, 256 WGs x 128 thr) ----------------
// WG g: jt = g&31 (16 j-cols), mg = g>>5 (32 rows). Wave w: rows mg*32+w*16.
// Weights for this WG's 16 cols x 3 gates (hi+lo) live in LDS for all 257 steps.
// LDS layout: row r = gate*32 + hl*16 + col (96 rows x 1024B), byte within row
// swizzled by ^((col&7)<<4) to break the stride-1024 bank conflict.
__global__ __launch_bounds__(128) void k_scan(
        const int* __restrict__ goal, const int* __restrict__ stem,
        const float* __restrict__ stem_emb,
        const s16* __restrict__ w_hi, const s16* __restrict__ w_lo,
        const float* __restrict__ b_hh, const float* __restrict__ gi_tok,
        s16* __restrict__ sph0, s16* __restrict__ spl0,
        s16* __restrict__ sph1, s16* __restrict__ spl1,
        float* __restrict__ hs, unsigned* bar) {
    __shared__ s16 wlds[96 * 512];   // 96 KB
    const int tid = threadIdx.x;
    const int wg = blockIdx.x;
    const int jt = wg & 31;
    const int mg = wg >> 5;
    const int w = tid >> 6;
    const int l = tid & 63;
    const int ln = l & 15;
    const int kg = l >> 4;
    const int mt = mg * 2 + w;
    const int row0 = mt * 16;
    const int j = jt * 16 + ln;
    const unsigned swz = (unsigned)((ln & 7) << 4);

    // one-time: stage weight slice into LDS (swizzled)
    for (int i = tid; i < 96 * 64; i += 128) {
        int rrow = i >> 6;            // 0..95
        int seg = i & 63;             // 16B segment within the 1KB row
        int gate = rrow >> 5;
        int hl = (rrow >> 4) & 1;
        int col = rrow & 15;
        const s16* src = (hl ? w_lo : w_hi) +
                         ((size_t)(gate * H + jt * 16 + col) * H) + seg * 8;
        int dstb = rrow * 1024 + ((seg * 16) ^ ((col & 7) << 4));
        *(s16x8*)((char*)wlds + dstb) = *(const s16x8*)src;
    }
    // one-time: h0 gather -> hs[0] fp32 + ping parity0 split
    {
        int idx = wg * 128 + tid;     // 0..32767 float4s = B*H/4
        int b = idx >> 7;
        int c4 = idx & 127;
        float4 v = ((const float4*)(stem_emb + (size_t)stem[b] * H))[c4];
        ((float4*)(hs + (size_t)b * H))[c4] = v;
        float xs[4] = {v.x, v.y, v.z, v.w};
        s16x4 h4, l4;
        #pragma unroll
        for (int q = 0; q < 4; ++q) {
            s16 hh = f2bf(xs[q]);
            h4[q] = hh;
            l4[q] = f2bf(xs[q] - bf2f(hh));
        }
        *(s16x4*)(sph0 + (size_t)b * H + c4 * 4) = h4;
        *(s16x4*)(spl0 + (size_t)b * H + c4 * 4) = l4;
    }
    gridbar(bar, wg, 1u, tid);

    const float bhr = b_hh[j], bhz = b_hh[H + j], bhn = b_hh[2 * H + j];

    for (int t = 0; t <= L; ++t) {
        const s16* hin_h = (t & 1) ? sph1 : sph0;
        const s16* hin_l = (t & 1) ? spl1 : spl0;
        s16* out_h = (t & 1) ? sph0 : sph1;
        s16* out_l = (t & 1) ? spl0 : spl1;
        const float* hp_src = hs + (size_t)t * SLOT;
        float* h_out = (t < L) ? (hs + (size_t)(t + 1) * SLOT) : hs;  // EOS -> slot 0

        const s16* ah = hin_h + (size_t)(row0 + ln) * H + kg * 8;
        const s16* al = hin_l + (size_t)(row0 + ln) * H + kg * 8;

        f32x4v ar{}, az{}, an{};
        #pragma unroll 4
        for (int kc = 0; kc < H; kc += 32) {
            s16x8 Ah = *(const s16x8*)(ah + kc);
            s16x8 Al = *(const s16x8*)(al + kc);
            const unsigned kb = ((unsigned)(kc * 2 + kg * 16)) ^ swz;
            const char* base = (const char*)wlds + ln * 1024 + kb;
            s16x8 Rh = *(const s16x8*)(base + 0 * 16384);
            s16x8 Rl = *(const s16x8*)(base + 1 * 16384);
            s16x8 Zh = *(const s16x8*)(base + 2 * 16384);
            s16x8 Zl = *(const s16x8*)(base + 3 * 16384);
            s16x8 Nh = *(const s16x8*)(base + 4 * 16384);
            s16x8 Nl = *(const s16x8*)(base + 5 * 16384);
            ar = __builtin_amdgcn_mfma_f32_16x16x32_bf16(Ah, Rh, ar, 0, 0, 0);
            az = __builtin_amdgcn_mfma_f32_16x16x32_bf16(Ah, Zh, az, 0, 0, 0);
            an = __builtin_amdgcn_mfma_f32_16x16x32_bf16(Ah, Nh, an, 0, 0, 0);
            ar = __builtin_amdgcn_mfma_f32_16x16x32_bf16(Ah, Rl, ar, 0, 0, 0);
            az = __builtin_amdgcn_mfma_f32_16x16x32_bf16(Ah, Zl, az, 0, 0, 0);
            an = __builtin_amdgcn_mfma_f32_16x16x32_bf16(Ah, Nl, an, 0, 0, 0);
            ar = __builtin_amdgcn_mfma_f32_16x16x32_bf16(Al, Rh, ar, 0, 0, 0);
            az = __builtin_amdgcn_mfma_f32_16x16x32_bf16(Al, Zh, az, 0, 0, 0);
            an = __builtin_amdgcn_mfma_f32_16x16x32_bf16(Al, Nh, an, 0, 0, 0);
        }

        #pragma unroll
        for (int q = 0; q < 4; ++q) {
            const int b = row0 + kg * 4 + q;   // C row = (l>>4)*4 + q
            const int v = (t < L) ? goal[(size_t)b * L + t] : EOS_TOK;
            const float* gi = gi_tok + (size_t)v * H3;
            float r = sigmoidf_(gi[j] + ar[q] + bhr);
            float z = sigmoidf_(gi[H + j] + az[q] + bhz);
            float nn = tanhf(gi[2 * H + j] + r * (an[q] + bhn));
            float hp = hp_src[(size_t)b * H + j];
            float hn = (1.f - z) * nn + z * hp;
            h_out[(size_t)b * H + j] = hn;
            s16 hb = f2bf(hn);
            out_h[(size_t)b * H + j] = hb;
            out_l[(size_t)b * H + j] = f2bf(hn - bf2f(hb));
        }

        if (t < L) gridbar(bar, wg, (unsigned)(t + 2), tid);
    }
}

// ---------------- fused MLP via MFMA ----------------
__global__ __launch_bounds__(256, 1) void k_mlp_mfma(
        const float* __restrict__ states,
        const s16* __restrict__ w0h, const s16* __restrict__ w0l,
        const float* __restrict__ b0v,
        const s16* __restrict__ w1h, const s16* __restrict__ w1l,
        const float* __restrict__ b1v,
        const float* __restrict__ w2v, const float* __restrict__ b2v,
        float* __restrict__ out, int col0) {
    __shared__ float v1s[64 * 512];   // 128 KB
    __shared__ float red[4][64];
    const int tid = threadIdx.x;
    const int wid = tid >> 6;
    const int l = tid & 63;
    const int ln = l & 15;
    const int kg = l >> 4;
    const int r0 = blockIdx.x * 64;
    const int col = col0 + (r0 >> 8);
    const int b0 = r0 & 255;

    f32x4v acc[4][8];
    #pragma unroll
    for (int mf = 0; mf < 4; ++mf)
        #pragma unroll
        for (int nf = 0; nf < 8; ++nf) acc[mf][nf] = f32x4v{};

    // ---- GEMM1: v1 = relu(relu(h) @ w0.T + b0) ----
    for (int kc = 0; kc < H; kc += 32) {
        s16x8 Ah[4], Al[4];
        #pragma unroll
        for (int mf = 0; mf < 4; ++mf) {
            const float* ap = states + (size_t)(r0 + mf * 16 + ln) * H + kc + kg * 8;
            float4 x0 = *(const float4*)ap;
            float4 x1 = *(const float4*)(ap + 4);
            float y[8] = {fmaxf(x0.x,0.f), fmaxf(x0.y,0.f), fmaxf(x0.z,0.f), fmaxf(x0.w,0.f),
                          fmaxf(x1.x,0.f), fmaxf(x1.y,0.f), fmaxf(x1.z,0.f), fmaxf(x1.w,0.f)};
            #pragma unroll
            for (int i = 0; i < 8; ++i) {
                s16 hh = f2bf(y[i]);
                Ah[mf][i] = hh;
                Al[mf][i] = f2bf(y[i] - bf2f(hh));
            }
        }
        #pragma unroll
        for (int nf = 0; nf < 8; ++nf) {
            const int n = wid * 128 + nf * 16 + ln;
            s16x8 Bh = *(const s16x8*)(w0h + (size_t)n * H + kc + kg * 8);
            s16x8 Bl = *(const s16x8*)(w0l + (size_t)n * H + kc + kg * 8);
            #pragma unroll
            for (int mf = 0; mf < 4; ++mf) {
                acc[mf][nf] = __builtin_amdgcn_mfma_f32_16x16x32_bf16(Ah[mf], Bh, acc[mf][nf], 0, 0, 0);
                acc[mf][nf] = __builtin_amdgcn_mfma_f32_16x16x32_bf16(Ah[mf], Bl, acc[mf][nf], 0, 0, 0);
                acc[mf][nf] = __builtin_amdgcn_mfma_f32_16x16x32_bf16(Al[mf], Bh, acc[mf][nf], 0, 0, 0);
            }
        }
    }
    float bn[8];
    #pragma unroll
    for (int nf = 0; nf < 8; ++nf) bn[nf] = b0v[wid * 128 + nf * 16 + ln];
    #pragma unroll
    for (int mf = 0; mf < 4; ++mf)
        #pragma unroll
        for (int nf = 0; nf < 8; ++nf)
            #pragma unroll
            for (int q = 0; q < 4; ++q) {
                int m = mf * 16 + kg * 4 + q;
                int n = wid * 128 + nf * 16 + ln;
                v1s[m * 512 + (n ^ ((m & 7) << 2))] = fmaxf(acc[mf][nf][q] + bn[nf], 0.f);
            }
    __syncthreads();

    // ---- GEMM2: v2 = relu(v1 @ w1.T + b1); lik = v2 . w2 ----
    #pragma unroll
    for (int mf = 0; mf < 4; ++mf)
        #pragma unroll
        for (int nf = 0; nf < 8; ++nf) acc[mf][nf] = f32x4v{};
    for (int kc = 0; kc < H; kc += 32) {
        s16x8 Ah[4], Al[4];
        #pragma unroll
        for (int mf = 0; mf < 4; ++mf) {
            const int rr = mf * 16 + ln;
            const int c = (rr & 7) << 2;
            const int k0 = kc + kg * 8;
            float4 y0 = *(const float4*)(v1s + rr * 512 + (k0 ^ c));
            float4 y1 = *(const float4*)(v1s + rr * 512 + ((k0 + 4) ^ c));
            float y[8] = {y0.x, y0.y, y0.z, y0.w, y1.x, y1.y, y1.z, y1.w};
            #pragma unroll
            for (int i = 0; i < 8; ++i) {
                s16 hh = f2bf(y[i]);
                Ah[mf][i] = hh;
                Al[mf][i] = f2bf(y[i] - bf2f(hh));
            }
        }
        #pragma unroll
        for (int nf = 0; nf < 8; ++nf) {
            const int n = wid * 128 + nf * 16 + ln;
            s16x8 Bh = *(const s16x8*)(w1h + (size_t)n * H + kc + kg * 8);
            s16x8 Bl = *(const s16x8*)(w1l + (size_t)n * H + kc + kg * 8);
            #pragma unroll
            for (int mf = 0; mf < 4; ++mf) {
                acc[mf][nf] = __builtin_amdgcn_mfma_f32_16x16x32_bf16(Ah[mf], Bh, acc[mf][nf], 0, 0, 0);
                acc[mf][nf] = __builtin_amdgcn_mfma_f32_16x16x32_bf16(Ah[mf], Bl, acc[mf][nf], 0, 0, 0);
                acc[mf][nf] = __builtin_amdgcn_mfma_f32_16x16x32_bf16(Al[mf], Bh, acc[mf][nf], 0, 0, 0);
            }
        }
    }
    float b1n[8], w2n[8];
    #pragma unroll
    for (int nf = 0; nf < 8; ++nf) {
        int n = wid * 128 + nf * 16 + ln;
        b1n[nf] = b1v[n];
        w2n[nf] = w2v[n];
    }
    float psum[4][4];
    #pragma unroll
    for (int mf = 0; mf < 4; ++mf)
        #pragma unroll
        for (int q = 0; q < 4; ++q) {
            float s = 0.f;
            #pragma unroll
            for (int nf = 0; nf < 8; ++nf)
                s += fmaxf(acc[mf][nf][q] + b1n[nf], 0.f) * w2n[nf];
            psum[mf][q] = s;
        }
    #pragma unroll
    for (int mf = 0; mf < 4; ++mf)
        #pragma unroll
        for (int q = 0; q < 4; ++q) {
            float s = psum[mf][q];
            #pragma unroll
            for (int msk = 1; msk < 16; msk <<= 1)
                s += __shfl_xor(s, msk, 64);
            psum[mf][q] = s;
        }
    if (ln == 0) {
        #pragma unroll
        for (int mf = 0; mf < 4; ++mf)
            #pragma unroll
            for (int q = 0; q < 4; ++q)
                red[wid][mf * 16 + kg * 4 + q] = psum[mf][q];
    }
    __syncthreads();
    if (tid < 64) {
        float s = b2v[0] + red[0][tid] + red[1][tid] + red[2][tid] + red[3][tid];
        out[(size_t)(b0 + tid) * OUTC + col] = s;
    }
}

extern "C" void kernel_launch(void* const* d_in, const int* in_sizes, int n_in,
                              void* d_out, int out_size, void* d_ws, size_t ws_size,
                              hipStream_t stream) {
    (void)in_sizes; (void)n_in; (void)out_size; (void)ws_size;
    const int* stem = (const int*)d_in[0];
    const int* goal = (const int*)d_in[1];
    const float* stem_emb = (const float*)d_in[2];
    const float* token_emb = (const float*)d_in[3];
    const float* w_ih = (const float*)d_in[4];
    const float* w_hh = (const float*)d_in[5];
    const float* b_ih = (const float*)d_in[6];
    const float* b_hh = (const float*)d_in[7];
    const float* w0 = (const float*)d_in[8];
    const float* b0 = (const float*)d_in[9];
    const float* w1 = (const float*)d_in[10];
    const float* b1 = (const float*)d_in[11];
    const float* w2 = (const float*)d_in[12];
    const float* b2 = (const float*)d_in[13];
    float* out = (float*)d_out;

    char* p = (char*)d_ws;
    float* gi_tok = (float*)p;      p += (size_t)TOKV * H3 * 4;
    s16* whh_h = (s16*)p;           p += (size_t)H3 * H * 2;
    s16* whh_l = (s16*)p;           p += (size_t)H3 * H * 2;
    s16* w0h = (s16*)p;             p += (size_t)H * H * 2;
    s16* w0l = (s16*)p;             p += (size_t)H * H * 2;
    s16* w1h = (s16*)p;             p += (size_t)H * H * 2;
    s16* w1l = (s16*)p;             p += (size_t)H * H * 2;
    s16* sph0 = (s16*)p;            p += SLOT * 2;
    s16* spl0 = (s16*)p;            p += SLOT * 2;
    s16* sph1 = (s16*)p;            p += SLOT * 2;
    s16* spl1 = (s16*)p;            p += SLOT * 2;
    unsigned* bar = (unsigned*)p;   p += 4096;
    float* hs = (float*)p;          // 257 slots

    hipMemsetAsync(bar, 0, 4096, stream);

    // prep
    k_split<<<768, 256, 0, stream>>>(w_hh, whh_h, whh_l, H3 * H / 4);
    k_split<<<256, 256, 0, stream>>>(w0, w0h, w0l, H * H / 4);
    k_split<<<256, 256, 0, stream>>>(w1, w1h, w1l, H * H / 4);
    k_gi_tok<<<128, 256, 0, stream>>>(token_emb, w_ih, b_ih, gi_tok);

    // persistent cooperative scan (h0 init + 256 GRU steps + EOS step)
    {
        const int* goal_a = goal;
        const int* stem_a = stem;
        const float* stem_emb_a = stem_emb;
        const s16* whh_h_a = whh_h;
        const s16* whh_l_a = whh_l;
        const float* b_hh_a = b_hh;
        const float* gi_tok_a = gi_tok;
        s16* sph0_a = sph0; s16* spl0_a = spl0;
        s16* sph1_a = sph1; s16* spl1_a = spl1;
        float* hs_a = hs;
        unsigned* bar_a = bar;
        void* kargs[] = {(void*)&goal_a, (void*)&stem_a, (void*)&stem_emb_a,
                         (void*)&whh_h_a, (void*)&whh_l_a, (void*)&b_hh_a,
                         (void*)&gi_tok_a, (void*)&sph0_a, (void*)&spl0_a,
                         (void*)&sph1_a, (void*)&spl1_a, (void*)&hs_a,
                         (void*)&bar_a};
        hipLaunchCooperativeKernel((void*)k_scan, dim3(256), dim3(128),
                                   kargs, 0, stream);
    }

    // MLP: cols 1..256 from hs[1..256], col 0 (EOS) from hs[0]
    k_mlp_mfma<<<1024, 256, 0, stream>>>(hs + SLOT, w0h, w0l, b0,
                                         w1h, w1l, b1, w2, b2, out, 1);
    k_mlp_mfma<<<4, 256, 0, stream>>>(hs, w0h, w0l, b0,
                                      w1h, w1l, b1, w2, b2, out, 0);
}

// Round 5
// 4261.897 us; speedup vs baseline: 2.1103x; 2.1103x over previous
//
#include <hip/hip_runtime.h>
#include <math.h>

#define B 256
#define L 256
#define H 512
#define H3 1536
#define TOKV 128
#define EOS_TOK 1
#define OUTC 257
#define SLOT ((size_t)B * H)   // floats per h-state

typedef short s16;
typedef s16 s16x8 __attribute__((ext_vector_type(8)));
typedef s16 s16x4 __attribute__((ext_vector_type(4)));
typedef float f32x4v __attribute__((ext_vector_type(4)));

__device__ __forceinline__ float sigmoidf_(float x) {
    return 1.0f / (1.0f + __expf(-x));
}

// fp32 -> bf16 bit pattern, round-to-nearest-even (same as (__bf16) cast)
__device__ __forceinline__ s16 f2bf(float x) {
    unsigned u = __builtin_bit_cast(unsigned, x);
    u += 0x7fffu + ((u >> 16) & 1u);
    return (s16)(u >> 16);
}
__device__ __forceinline__ float bf2f(s16 h) {
    return __builtin_bit_cast(float, ((unsigned)(unsigned short)h) << 16);
}

// ---------------- per-cluster barrier (monotonic counter) ----------------
// Cluster c: counter at bar[c*32]. Monotonic: barrier #n waits for 32*n.
// Release: tid0's RELEASE add (wbl2) — all threads' stores are already in L2
// because __syncthreads drains vmcnt. Acquire: the spin load is ACQUIRE (inv
// between observing the count and reading data). Counters zeroed once per
// kernel_launch via hipMemsetAsync -> deterministic across graph replays.
__device__ __forceinline__ void clusterbar(unsigned* bar, int c, unsigned n, int tid) {
    __syncthreads();   // drains vmcnt: all stores of all threads are out of the waves
    if (tid == 0) {
        const unsigned tgt = 32u * n;
        unsigned* ctr = bar + c * 32;
        __hip_atomic_fetch_add(ctr, 1u, __ATOMIC_RELEASE, __HIP_MEMORY_SCOPE_AGENT);
        while (__hip_atomic_load(ctr, __ATOMIC_ACQUIRE, __HIP_MEMORY_SCOPE_AGENT) < tgt)
            __builtin_amdgcn_s_sleep(1);
    }
    __syncthreads();
}

// ---------------- prep: elementwise split of a fp32 weight array ----------------
__global__ __launch_bounds__(256) void k_split(const float* __restrict__ src,
                                               s16* __restrict__ hi,
                                               s16* __restrict__ lo, int n4) {
    int i = blockIdx.x * 256 + threadIdx.x;
    if (i >= n4) return;
    float4 x = ((const float4*)src)[i];
    float xs[4] = {x.x, x.y, x.z, x.w};
    s16x4 h, l;
    #pragma unroll
    for (int q = 0; q < 4; ++q) {
        s16 hh = f2bf(xs[q]);
        h[q] = hh;
        l[q] = f2bf(xs[q] - bf2f(hh));
    }
    *(s16x4*)(hi + (size_t)i * 4) = h;
    *(s16x4*)(lo + (size_t)i * 4) = l;
}

// ---------------- prep: gi_tok[v][j] = relu(token_emb[v]) . w_ih[j] + b_ih[j] (fp32) ----------------
__global__ __launch_bounds__(256) void k_gi_tok(
        const float* __restrict__ token_emb, const float* __restrict__ w_ih,
        const float* __restrict__ b_ih, float* __restrict__ gi_out) {
    __shared__ float wlds[96][132];
    __shared__ float elds[16][132];
    const int vi = blockIdx.x >> 4;
    const int ji = blockIdx.x & 15;
    const int v0 = vi << 4, j0 = ji * 96;
    const int tid = threadIdx.x;
    const int vl = tid & 7;
    const int jl = tid >> 3;
    float acc[2][3] = {{0.f, 0.f, 0.f}, {0.f, 0.f, 0.f}};
    for (int ck = 0; ck < 4; ++ck) {
        const int c0 = ck << 7;
        __syncthreads();
        for (int i = tid; i < 96 * 32; i += 256) {
            int row = i >> 5, c4 = i & 31;
            *(float4*)&wlds[row][c4 << 2] =
                *(const float4*)(w_ih + (size_t)(j0 + row) * H + c0 + (c4 << 2));
        }
        for (int i = tid; i < 16 * 32; i += 256) {
            int row = i >> 5, c4 = i & 31;
            float4 e = *(const float4*)(token_emb + (size_t)(v0 + row) * H + c0 + (c4 << 2));
            e.x = fmaxf(e.x, 0.f); e.y = fmaxf(e.y, 0.f);
            e.z = fmaxf(e.z, 0.f); e.w = fmaxf(e.w, 0.f);
            *(float4*)&elds[row][c4 << 2] = e;
        }
        __syncthreads();
        #pragma unroll 8
        for (int c = 0; c < 128; c += 4) {
            float4 wa = *(const float4*)&wlds[jl][c];
            float4 wb = *(const float4*)&wlds[32 + jl][c];
            float4 wc = *(const float4*)&wlds[64 + jl][c];
            float4 ea = *(const float4*)&elds[vl][c];
            float4 eb = *(const float4*)&elds[vl + 8][c];
            acc[0][0] += ea.x*wa.x + ea.y*wa.y + ea.z*wa.z + ea.w*wa.w;
            acc[0][1] += ea.x*wb.x + ea.y*wb.y + ea.z*wb.z + ea.w*wb.w;
            acc[0][2] += ea.x*wc.x + ea.y*wc.y + ea.z*wc.z + ea.w*wc.w;
            acc[1][0] += eb.x*wa.x + eb.y*wa.y + eb.z*wa.z + eb.w*wa.w;
            acc[1][1] += eb.x*wb.x + eb.y*wb.y + eb.z*wb.z + eb.w*wb.w;
            acc[1][2] += eb.x*wc.x + eb.y*wc.y + eb.z*wc.z + eb.w*wc.w;
        }
    }
    #pragma unroll
    for (int p = 0; p < 2; ++p) {
        int v = v0 + vl + (p << 3);
        #pragma unroll
        for (int s = 0; s < 3; ++s) {
            int j = j0 + (s << 5) + jl;
            gi_out[(size_t)v * H3 + j] = acc[p][s] + b_ih[j];
        }
    }
}

// ---------------- persistent GRU scan, clustered (cooperative, 256 WGs x 128 thr) ----------------
// WG wg: cluster c = wg&7 (owns batch rows c*32..c*32+31), j-slice jt = wg>>3
// (cols jt*16..+16). Weights for this WG's 16 cols x 3 gates (hi+lo) are
// pre-packed FRAGMENT-MAJOR in LDS: [g2][kc][lane][8] so every ds_read_b128 is
// lane-contiguous (conflict-free). Only the cluster's 32 WGs sync per step.
__global__ __launch_bounds__(128) void k_scan(
        const int* __restrict__ goal, const int* __restrict__ stem,
        const float* __restrict__ stem_emb,
        const s16* __restrict__ w_hi, const s16* __restrict__ w_lo,
        const float* __restrict__ b_hh, const float* __restrict__ gi_tok,
        s16* __restrict__ sph0, s16* __restrict__ spl0,
        s16* __restrict__ sph1, s16* __restrict__ spl1,
        float* __restrict__ hs, unsigned* bar) {
    __shared__ s16 wlds[96 * 512];   // 96 KB, viewed as [6][16][64][8]
    const int tid = threadIdx.x;
    const int wg = blockIdx.x;
    const int c = wg & 7;
    const int jt = wg >> 3;
    const int w = tid >> 6;
    const int l = tid & 63;
    const int ln = l & 15;
    const int kg = l >> 4;
    const int row0 = c * 32 + w * 16;   // this wave's 16 batch rows
    const int j = jt * 16 + ln;

    // one-time: stage weight slice into LDS, fragment-major.
    // seg i = (g2*16 + kcIdx)*64 + lane ; lane=(lnn + kgg*16)
    // holds W_{gate,hl}[jt*16+lnn][kcIdx*32 + kgg*8 .. +8]
    for (int i = tid; i < 6144; i += 128) {
        int lane = i & 63;
        int chunk = i >> 6;           // 0..95 = g2*16 + kcIdx
        int g2 = chunk >> 4;          // gate*2 + hl
        int kcIdx = chunk & 15;
        int gate = g2 >> 1, hl = g2 & 1;
        int lnn = lane & 15, kgg = lane >> 4;
        const s16* src = (hl ? w_lo : w_hi) +
                         ((size_t)(gate * H + jt * 16 + lnn)) * H + kcIdx * 32 + kgg * 8;
        *(s16x8*)(wlds + (size_t)i * 8) = *(const s16x8*)src;
    }
    // one-time: h0 split into ping parity0 for this cluster's rows.
    // WG jt inits row c*32+jt (b uniform across the WG), col段 = tid.
    {
        int b = c * 32 + jt;
        int c4 = tid;                 // 0..127 float4s
        float4 v = ((const float4*)(stem_emb + (size_t)stem[b] * H))[c4];
        float xs[4] = {v.x, v.y, v.z, v.w};
        #pragma unroll
        for (int q = 0; q < 4; ++q) {
            s16 hh = f2bf(xs[q]);
            __builtin_nontemporal_store(hh, sph0 + (size_t)b * H + c4 * 4 + q);
            __builtin_nontemporal_store(f2bf(xs[q] - bf2f(hh)), spl0 + (size_t)b * H + c4 * 4 + q);
        }
    }
    clusterbar(bar, c, 1u, tid);

    const float bhr = b_hh[j], bhz = b_hh[H + j], bhn = b_hh[2 * H + j];

    for (int t = 0; t <= L; ++t) {
        const s16* hin_h = (t & 1) ? sph1 : sph0;
        const s16* hin_l = (t & 1) ? spl1 : spl0;
        s16* out_h = (t & 1) ? sph0 : sph1;
        s16* out_l = (t & 1) ? spl0 : spl1;
        float* h_out = (t < L) ? (hs + (size_t)(t + 1) * SLOT) : hs;  // EOS -> slot 0

        const s16* ahp = hin_h + (size_t)(row0 + ln) * H + kg * 8;
        const s16* alp = hin_l + (size_t)(row0 + ln) * H + kg * 8;

        f32x4v ar{}, az{}, an{};
        #pragma unroll 4
        for (int kcIdx = 0; kcIdx < 16; ++kcIdx) {
            s16x8 Ah = *(const s16x8*)(ahp + kcIdx * 32);
            s16x8 Al = *(const s16x8*)(alp + kcIdx * 32);
            const s16* bb = wlds + ((size_t)(kcIdx * 64 + l)) * 8;   // g2=0; stride 8192 elems per g2
            s16x8 Rh = *(const s16x8*)(bb);
            s16x8 Rl = *(const s16x8*)(bb + 8192);
            s16x8 Zh = *(const s16x8*)(bb + 16384);
            s16x8 Zl = *(const s16x8*)(bb + 24576);
            s16x8 Nh = *(const s16x8*)(bb + 32768);
            s16x8 Nl = *(const s16x8*)(bb + 40960);
            ar = __builtin_amdgcn_mfma_f32_16x16x32_bf16(Ah, Rh, ar, 0, 0, 0);
            az = __builtin_amdgcn_mfma_f32_16x16x32_bf16(Ah, Zh, az, 0, 0, 0);
            an = __builtin_amdgcn_mfma_f32_16x16x32_bf16(Ah, Nh, an, 0, 0, 0);
            ar = __builtin_amdgcn_mfma_f32_16x16x32_bf16(Ah, Rl, ar, 0, 0, 0);
            az = __builtin_amdgcn_mfma_f32_16x16x32_bf16(Ah, Zl, az, 0, 0, 0);
            an = __builtin_amdgcn_mfma_f32_16x16x32_bf16(Ah, Nl, an, 0, 0, 0);
            ar = __builtin_amdgcn_mfma_f32_16x16x32_bf16(Al, Rh, ar, 0, 0, 0);
            az = __builtin_amdgcn_mfma_f32_16x16x32_bf16(Al, Zh, az, 0, 0, 0);
            an = __builtin_amdgcn_mfma_f32_16x16x32_bf16(Al, Nh, an, 0, 0, 0);
        }

        #pragma unroll
        for (int q = 0; q < 4; ++q) {
            const int b = row0 + kg * 4 + q;   // C row = (l>>4)*4 + q
            const int v = (t < L) ? goal[(size_t)b * L + t] : EOS_TOK;
            const float* gi = gi_tok + (size_t)v * H3;
            float r = sigmoidf_(gi[j] + ar[q] + bhr);
            float z = sigmoidf_(gi[H + j] + az[q] + bhz);
            float nn = tanhf(gi[2 * H + j] + r * (an[q] + bhn));
            float hp = bf2f(hin_h[(size_t)b * H + j]) + bf2f(hin_l[(size_t)b * H + j]);
            float hn = (1.f - z) * nn + z * hp;
            __builtin_nontemporal_store(hn, h_out + (size_t)b * H + j);
            s16 hb = f2bf(hn);
            __builtin_nontemporal_store(hb, out_h + (size_t)b * H + j);
            __builtin_nontemporal_store(f2bf(hn - bf2f(hb)), out_l + (size_t)b * H + j);
        }

        if (t < L) clusterbar(bar, c, (unsigned)(t + 2), tid);
    }
}

// ---------------- fused MLP via MFMA ----------------
__global__ __launch_bounds__(256, 1) void k_mlp_mfma(
        const float* __restrict__ states,
        const s16* __restrict__ w0h, const s16* __restrict__ w0l,
        const float* __restrict__ b0v,
        const s16* __restrict__ w1h, const s16* __restrict__ w1l,
        const float* __restrict__ b1v,
        const float* __restrict__ w2v, const float* __restrict__ b2v,
        float* __restrict__ out, int col0) {
    __shared__ float v1s[64 * 512];   // 128 KB
    __shared__ float red[4][64];
    const int tid = threadIdx.x;
    const int wid = tid >> 6;
    const int l = tid & 63;
    const int ln = l & 15;
    const int kg = l >> 4;
    const int r0 = blockIdx.x * 64;
    const int col = col0 + (r0 >> 8);
    const int b0 = r0 & 255;

    f32x4v acc[4][8];
    #pragma unroll
    for (int mf = 0; mf < 4; ++mf)
        #pragma unroll
        for (int nf = 0; nf < 8; ++nf) acc[mf][nf] = f32x4v{};

    // ---- GEMM1: v1 = relu(relu(h) @ w0.T + b0) ----
    for (int kc = 0; kc < H; kc += 32) {
        s16x8 Ah[4], Al[4];
        #pragma unroll
        for (int mf = 0; mf < 4; ++mf) {
            const float* ap = states + (size_t)(r0 + mf * 16 + ln) * H + kc + kg * 8;
            float4 x0 = *(const float4*)ap;
            float4 x1 = *(const float4*)(ap + 4);
            float y[8] = {fmaxf(x0.x,0.f), fmaxf(x0.y,0.f), fmaxf(x0.z,0.f), fmaxf(x0.w,0.f),
                          fmaxf(x1.x,0.f), fmaxf(x1.y,0.f), fmaxf(x1.z,0.f), fmaxf(x1.w,0.f)};
            #pragma unroll
            for (int i = 0; i < 8; ++i) {
                s16 hh = f2bf(y[i]);
                Ah[mf][i] = hh;
                Al[mf][i] = f2bf(y[i] - bf2f(hh));
            }
        }
        #pragma unroll
        for (int nf = 0; nf < 8; ++nf) {
            const int n = wid * 128 + nf * 16 + ln;
            s16x8 Bh = *(const s16x8*)(w0h + (size_t)n * H + kc + kg * 8);
            s16x8 Bl = *(const s16x8*)(w0l + (size_t)n * H + kc + kg * 8);
            #pragma unroll
            for (int mf = 0; mf < 4; ++mf) {
                acc[mf][nf] = __builtin_amdgcn_mfma_f32_16x16x32_bf16(Ah[mf], Bh, acc[mf][nf], 0, 0, 0);
                acc[mf][nf] = __builtin_amdgcn_mfma_f32_16x16x32_bf16(Ah[mf], Bl, acc[mf][nf], 0, 0, 0);
                acc[mf][nf] = __builtin_amdgcn_mfma_f32_16x16x32_bf16(Al[mf], Bh, acc[mf][nf], 0, 0, 0);
            }
        }
    }
    float bn[8];
    #pragma unroll
    for (int nf = 0; nf < 8; ++nf) bn[nf] = b0v[wid * 128 + nf * 16 + ln];
    #pragma unroll
    for (int mf = 0; mf < 4; ++mf)
        #pragma unroll
        for (int nf = 0; nf < 8; ++nf)
            #pragma unroll
            for (int q = 0; q < 4; ++q) {
                int m = mf * 16 + kg * 4 + q;
                int n = wid * 128 + nf * 16 + ln;
                v1s[m * 512 + (n ^ ((m & 7) << 2))] = fmaxf(acc[mf][nf][q] + bn[nf], 0.f);
            }
    __syncthreads();

    // ---- GEMM2: v2 = relu(v1 @ w1.T + b1); lik = v2 . w2 ----
    #pragma unroll
    for (int mf = 0; mf < 4; ++mf)
        #pragma unroll
        for (int nf = 0; nf < 8; ++nf) acc[mf][nf] = f32x4v{};
    for (int kc = 0; kc < H; kc += 32) {
        s16x8 Ah[4], Al[4];
        #pragma unroll
        for (int mf = 0; mf < 4; ++mf) {
            const int rr = mf * 16 + ln;
            const int c = (rr & 7) << 2;
            const int k0 = kc + kg * 8;
            float4 y0 = *(const float4*)(v1s + rr * 512 + (k0 ^ c));
            float4 y1 = *(const float4*)(v1s + rr * 512 + ((k0 + 4) ^ c));
            float y[8] = {y0.x, y0.y, y0.z, y0.w, y1.x, y1.y, y1.z, y1.w};
            #pragma unroll
            for (int i = 0; i < 8; ++i) {
                s16 hh = f2bf(y[i]);
                Ah[mf][i] = hh;
                Al[mf][i] = f2bf(y[i] - bf2f(hh));
            }
        }
        #pragma unroll
        for (int nf = 0; nf < 8; ++nf) {
            const int n = wid * 128 + nf * 16 + ln;
            s16x8 Bh = *(const s16x8*)(w1h + (size_t)n * H + kc + kg * 8);
            s16x8 Bl = *(const s16x8*)(w1l + (size_t)n * H + kc + kg * 8);
            #pragma unroll
            for (int mf = 0; mf < 4; ++mf) {
                acc[mf][nf] = __builtin_amdgcn_mfma_f32_16x16x32_bf16(Ah[mf], Bh, acc[mf][nf], 0, 0, 0);
                acc[mf][nf] = __builtin_amdgcn_mfma_f32_16x16x32_bf16(Ah[mf], Bl, acc[mf][nf], 0, 0, 0);
                acc[mf][nf] = __builtin_amdgcn_mfma_f32_16x16x32_bf16(Al[mf], Bh, acc[mf][nf], 0, 0, 0);
            }
        }
    }
    float b1n[8], w2n[8];
    #pragma unroll
    for (int nf = 0; nf < 8; ++nf) {
        int n = wid * 128 + nf * 16 + ln;
        b1n[nf] = b1v[n];
        w2n[nf] = w2v[n];
    }
    float psum[4][4];
    #pragma unroll
    for (int mf = 0; mf < 4; ++mf)
        #pragma unroll
        for (int q = 0; q < 4; ++q) {
            float s = 0.f;
            #pragma unroll
            for (int nf = 0; nf < 8; ++nf)
                s += fmaxf(acc[mf][nf][q] + b1n[nf], 0.f) * w2n[nf];
            psum[mf][q] = s;
        }
    #pragma unroll
    for (int mf = 0; mf < 4; ++mf)
        #pragma unroll
        for (int q = 0; q < 4; ++q) {
            float s = psum[mf][q];
            #pragma unroll
            for (int msk = 1; msk < 16; msk <<= 1)
                s += __shfl_xor(s, msk, 64);
            psum[mf][q] = s;
        }
    if (ln == 0) {
        #pragma unroll
        for (int mf = 0; mf < 4; ++mf)
            #pragma unroll
            for (int q = 0; q < 4; ++q)
                red[wid][mf * 16 + kg * 4 + q] = psum[mf][q];
    }
    __syncthreads();
    if (tid < 64) {
        float s = b2v[0] + red[0][tid] + red[1][tid] + red[2][tid] + red[3][tid];
        out[(size_t)(b0 + tid) * OUTC + col] = s;
    }
}

extern "C" void kernel_launch(void* const* d_in, const int* in_sizes, int n_in,
                              void* d_out, int out_size, void* d_ws, size_t ws_size,
                              hipStream_t stream) {
    (void)in_sizes; (void)n_in; (void)out_size; (void)ws_size;
    const int* stem = (const int*)d_in[0];
    const int* goal = (const int*)d_in[1];
    const float* stem_emb = (const float*)d_in[2];
    const float* token_emb = (const float*)d_in[3];
    const float* w_ih = (const float*)d_in[4];
    const float* w_hh = (const float*)d_in[5];
    const float* b_ih = (const float*)d_in[6];
    const float* b_hh = (const float*)d_in[7];
    const float* w0 = (const float*)d_in[8];
    const float* b0 = (const float*)d_in[9];
    const float* w1 = (const float*)d_in[10];
    const float* b1 = (const float*)d_in[11];
    const float* w2 = (const float*)d_in[12];
    const float* b2 = (const float*)d_in[13];
    float* out = (float*)d_out;

    char* p = (char*)d_ws;
    float* gi_tok = (float*)p;      p += (size_t)TOKV * H3 * 4;
    s16* whh_h = (s16*)p;           p += (size_t)H3 * H * 2;
    s16* whh_l = (s16*)p;           p += (size_t)H3 * H * 2;
    s16* w0h = (s16*)p;             p += (size_t)H * H * 2;
    s16* w0l = (s16*)p;             p += (size_t)H * H * 2;
    s16* w1h = (s16*)p;             p += (size_t)H * H * 2;
    s16* w1l = (s16*)p;             p += (size_t)H * H * 2;
    s16* sph0 = (s16*)p;            p += SLOT * 2;
    s16* spl0 = (s16*)p;            p += SLOT * 2;
    s16* sph1 = (s16*)p;            p += SLOT * 2;
    s16* spl1 = (s16*)p;            p += SLOT * 2;
    unsigned* bar = (unsigned*)p;   p += 4096;
    float* hs = (float*)p;          // 257 slots: [1..256]=post-step states, [0]=EOS final

    hipMemsetAsync(bar, 0, 4096, stream);

    // prep
    k_split<<<768, 256, 0, stream>>>(w_hh, whh_h, whh_l, H3 * H / 4);
    k_split<<<256, 256, 0, stream>>>(w0, w0h, w0l, H * H / 4);
    k_split<<<256, 256, 0, stream>>>(w1, w1h, w1l, H * H / 4);
    k_gi_tok<<<128, 256, 0, stream>>>(token_emb, w_ih, b_ih, gi_tok);

    // persistent clustered scan (h0 init + 256 GRU steps + EOS step)
    {
        const int* goal_a = goal;
        const int* stem_a = stem;
        const float* stem_emb_a = stem_emb;
        const s16* whh_h_a = whh_h;
        const s16* whh_l_a = whh_l;
        const float* b_hh_a = b_hh;
        const float* gi_tok_a = gi_tok;
        s16* sph0_a = sph0; s16* spl0_a = spl0;
        s16* sph1_a = sph1; s16* spl1_a = spl1;
        float* hs_a = hs;
        unsigned* bar_a = bar;
        void* kargs[] = {(void*)&goal_a, (void*)&stem_a, (void*)&stem_emb_a,
                         (void*)&whh_h_a, (void*)&whh_l_a, (void*)&b_hh_a,
                         (void*)&gi_tok_a, (void*)&sph0_a, (void*)&spl0_a,
                         (void*)&sph1_a, (void*)&spl1_a, (void*)&hs_a,
                         (void*)&bar_a};
        hipLaunchCooperativeKernel((void*)k_scan, dim3(256), dim3(128),
                                   kargs, 0, stream);
    }

    // MLP: cols 1..256 from hs[1..256], col 0 (EOS) from hs[0]
    k_mlp_mfma<<<1024, 256, 0, stream>>>(hs + SLOT, w0h, w0l, b0,
                                         w1h, w1l, b1, w2, b2, out, 1);
    k_mlp_mfma<<<4, 256, 0, stream>>>(hs, w0h, w0l, b0,
                                      w1h, w1l, b1, w2, b2, out, 0);
}

// Round 6
// 3405.620 us; speedup vs baseline: 2.6409x; 1.2514x over previous
//
#include <hip/hip_runtime.h>
#include <math.h>

#define B 256
#define L 256
#define H 512
#define H3 1536
#define TOKV 128
#define EOS_TOK 1
#define OUTC 257
#define SLOT ((size_t)B * H)   // elements per h-state

typedef short s16;
typedef s16 s16x8 __attribute__((ext_vector_type(8)));
typedef s16 s16x4 __attribute__((ext_vector_type(4)));
typedef float f32x4v __attribute__((ext_vector_type(4)));
typedef unsigned long long u64;

__device__ __forceinline__ float sigmoidf_(float x) {
    return 1.0f / (1.0f + __expf(-x));
}

// fp32 -> bf16 bit pattern, round-to-nearest-even (same as (__bf16) cast)
__device__ __forceinline__ s16 f2bf(float x) {
    unsigned u = __builtin_bit_cast(unsigned, x);
    u += 0x7fffu + ((u >> 16) & 1u);
    return (s16)(u >> 16);
}
__device__ __forceinline__ float bf2f(s16 h) {
    return __builtin_bit_cast(float, ((unsigned)(unsigned short)h) << 16);
}
// pack hi(low16)|lo(high16) of a float's 2-term bf16 split
__device__ __forceinline__ unsigned packsplit(float x) {
    s16 hh = f2bf(x);
    s16 ll = f2bf(x - bf2f(hh));
    return (unsigned)(unsigned short)hh | ((unsigned)(unsigned short)ll << 16);
}

// ---------------- per-cluster barrier (monotonic, fully relaxed) ----------------
// All communicated data flows through sc1 (agent-scope) loads/stores, so the
// barrier needs NO cache maintenance: __syncthreads drains vmcnt (sc1 stores
// globally visible), the relaxed agent add/load operate at the coherence point.
__device__ __forceinline__ void clusterbar(unsigned* bar, int c, unsigned n, int tid) {
    __syncthreads();
    if (tid == 0) {
        const unsigned tgt = 32u * n;
        unsigned* ctr = bar + c * 32;
        __hip_atomic_fetch_add(ctr, 1u, __ATOMIC_RELAXED, __HIP_MEMORY_SCOPE_AGENT);
        while (__hip_atomic_load(ctr, __ATOMIC_RELAXED, __HIP_MEMORY_SCOPE_AGENT) < tgt)
            __builtin_amdgcn_s_sleep(1);
    }
    __syncthreads();
}

// ---------------- prep: elementwise split of a fp32 weight array ----------------
__global__ __launch_bounds__(256) void k_split(const float* __restrict__ src,
                                               s16* __restrict__ hi,
                                               s16* __restrict__ lo, int n4) {
    int i = blockIdx.x * 256 + threadIdx.x;
    if (i >= n4) return;
    float4 x = ((const float4*)src)[i];
    float xs[4] = {x.x, x.y, x.z, x.w};
    s16x4 h, l;
    #pragma unroll
    for (int q = 0; q < 4; ++q) {
        s16 hh = f2bf(xs[q]);
        h[q] = hh;
        l[q] = f2bf(xs[q] - bf2f(hh));
    }
    *(s16x4*)(hi + (size_t)i * 4) = h;
    *(s16x4*)(lo + (size_t)i * 4) = l;
}

// ---------------- prep: gi_tok[v][j] = relu(token_emb[v]) . w_ih[j] + b_ih[j] (fp32) ----------------
__global__ __launch_bounds__(256) void k_gi_tok(
        const float* __restrict__ token_emb, const float* __restrict__ w_ih,
        const float* __restrict__ b_ih, float* __restrict__ gi_out) {
    __shared__ float wlds[96][132];
    __shared__ float elds[16][132];
    const int vi = blockIdx.x >> 4;
    const int ji = blockIdx.x & 15;
    const int v0 = vi << 4, j0 = ji * 96;
    const int tid = threadIdx.x;
    const int vl = tid & 7;
    const int jl = tid >> 3;
    float acc[2][3] = {{0.f, 0.f, 0.f}, {0.f, 0.f, 0.f}};
    for (int ck = 0; ck < 4; ++ck) {
        const int c0 = ck << 7;
        __syncthreads();
        for (int i = tid; i < 96 * 32; i += 256) {
            int row = i >> 5, c4 = i & 31;
            *(float4*)&wlds[row][c4 << 2] =
                *(const float4*)(w_ih + (size_t)(j0 + row) * H + c0 + (c4 << 2));
        }
        for (int i = tid; i < 16 * 32; i += 256) {
            int row = i >> 5, c4 = i & 31;
            float4 e = *(const float4*)(token_emb + (size_t)(v0 + row) * H + c0 + (c4 << 2));
            e.x = fmaxf(e.x, 0.f); e.y = fmaxf(e.y, 0.f);
            e.z = fmaxf(e.z, 0.f); e.w = fmaxf(e.w, 0.f);
            *(float4*)&elds[row][c4 << 2] = e;
        }
        __syncthreads();
        #pragma unroll 8
        for (int c = 0; c < 128; c += 4) {
            float4 wa = *(const float4*)&wlds[jl][c];
            float4 wb = *(const float4*)&wlds[32 + jl][c];
            float4 wc = *(const float4*)&wlds[64 + jl][c];
            float4 ea = *(const float4*)&elds[vl][c];
            float4 eb = *(const float4*)&elds[vl + 8][c];
            acc[0][0] += ea.x*wa.x + ea.y*wa.y + ea.z*wa.z + ea.w*wa.w;
            acc[0][1] += ea.x*wb.x + ea.y*wb.y + ea.z*wb.z + ea.w*wb.w;
            acc[0][2] += ea.x*wc.x + ea.y*wc.y + ea.z*wc.z + ea.w*wc.w;
            acc[1][0] += eb.x*wa.x + eb.y*wa.y + eb.z*wa.z + eb.w*wa.w;
            acc[1][1] += eb.x*wb.x + eb.y*wb.y + eb.z*wb.z + eb.w*wb.w;
            acc[1][2] += eb.x*wc.x + eb.y*wc.y + eb.z*wc.z + eb.w*wc.w;
        }
    }
    #pragma unroll
    for (int p = 0; p < 2; ++p) {
        int v = v0 + vl + (p << 3);
        #pragma unroll
        for (int s = 0; s < 3; ++s) {
            int j = j0 + (s << 5) + jl;
            gi_out[(size_t)v * H3 + j] = acc[p][s] + b_ih[j];
        }
    }
}

// ---------------- persistent GRU scan, clustered (cooperative, 256 WGs x 128 thr) ----------------
// WG wg: cluster c = wg&7 (owns batch rows c*32..c*32+31), j-slice jt = wg>>3.
// Weights in LDS fragment-major (conflict-free). h ping-pong is a packed u32
// buffer (bf16 hi | lo<<16) accessed ONLY via relaxed agent atomics (sc1) so
// inter-WG exchange is coherent with zero wbl2/inv traffic.
__global__ __launch_bounds__(128) void k_scan(
        const int* __restrict__ goal, const int* __restrict__ stem,
        const float* __restrict__ stem_emb,
        const s16* __restrict__ w_hi, const s16* __restrict__ w_lo,
        const float* __restrict__ b_hh, const float* __restrict__ gi_tok,
        unsigned* __restrict__ spk0, unsigned* __restrict__ spk1,
        float* __restrict__ hs, unsigned* bar) {
    __shared__ s16 wlds[96 * 512];   // 96 KB, viewed as [6][16][64][8]
    const int tid = threadIdx.x;
    const int wg = blockIdx.x;
    const int c = wg & 7;
    const int jt = wg >> 3;
    const int w = tid >> 6;
    const int l = tid & 63;
    const int ln = l & 15;
    const int kg = l >> 4;
    const int row0 = c * 32 + w * 16;   // this wave's 16 batch rows
    const int j = jt * 16 + ln;

    // one-time: stage weight slice into LDS, fragment-major.
    for (int i = tid; i < 6144; i += 128) {
        int lane = i & 63;
        int chunk = i >> 6;           // 0..95 = g2*16 + kcIdx
        int g2 = chunk >> 4;          // gate*2 + hl
        int kcIdx = chunk & 15;
        int gate = g2 >> 1, hl = g2 & 1;
        int lnn = lane & 15, kgg = lane >> 4;
        const s16* src = (hl ? w_lo : w_hi) +
                         ((size_t)(gate * H + jt * 16 + lnn)) * H + kcIdx * 32 + kgg * 8;
        *(s16x8*)(wlds + (size_t)i * 8) = *(const s16x8*)src;
    }
    // one-time: h0 split (packed) for this cluster's rows; WG jt inits row c*32+jt
    {
        int b = c * 32 + jt;
        int c4 = tid;                 // 0..127 float4s
        float4 v = ((const float4*)(stem_emb + (size_t)stem[b] * H))[c4];
        float xs[4] = {v.x, v.y, v.z, v.w};
        #pragma unroll
        for (int q = 0; q < 4; ++q)
            __hip_atomic_store(spk0 + (size_t)b * H + c4 * 4 + q, packsplit(xs[q]),
                               __ATOMIC_RELAXED, __HIP_MEMORY_SCOPE_AGENT);
    }
    clusterbar(bar, c, 1u, tid);

    const float bhr = b_hh[j], bhz = b_hh[H + j], bhn = b_hh[2 * H + j];

    for (int t = 0; t <= L; ++t) {
        unsigned* pin = (t & 1) ? spk1 : spk0;
        unsigned* pout = (t & 1) ? spk0 : spk1;
        float* h_out = (t < L) ? (hs + (size_t)(t + 1) * SLOT) : hs;  // EOS -> slot 0

        // A-fragment base in u64 units: row*(H/2) + kg*4
        u64* ap = (u64*)pin + (size_t)(row0 + ln) * (H / 2) + kg * 4;

        f32x4v ar{}, az{}, an{};
        #pragma unroll 4
        for (int kcIdx = 0; kcIdx < 16; ++kcIdx) {
            u64 wv[4];
            #pragma unroll
            for (int i = 0; i < 4; ++i)
                wv[i] = __hip_atomic_load(ap + kcIdx * 16 + i, __ATOMIC_RELAXED,
                                          __HIP_MEMORY_SCOPE_AGENT);
            s16x8 Ah, Al;
            #pragma unroll
            for (int i = 0; i < 4; ++i) {
                unsigned w0 = (unsigned)wv[i], w1 = (unsigned)(wv[i] >> 32);
                Ah[2*i]   = (s16)(w0 & 0xffff); Al[2*i]   = (s16)(w0 >> 16);
                Ah[2*i+1] = (s16)(w1 & 0xffff); Al[2*i+1] = (s16)(w1 >> 16);
            }
            const s16* bb = wlds + ((size_t)(kcIdx * 64 + l)) * 8;
            s16x8 Rh = *(const s16x8*)(bb);
            s16x8 Rl = *(const s16x8*)(bb + 8192);
            s16x8 Zh = *(const s16x8*)(bb + 16384);
            s16x8 Zl = *(const s16x8*)(bb + 24576);
            s16x8 Nh = *(const s16x8*)(bb + 32768);
            s16x8 Nl = *(const s16x8*)(bb + 40960);
            ar = __builtin_amdgcn_mfma_f32_16x16x32_bf16(Ah, Rh, ar, 0, 0, 0);
            az = __builtin_amdgcn_mfma_f32_16x16x32_bf16(Ah, Zh, az, 0, 0, 0);
            an = __builtin_amdgcn_mfma_f32_16x16x32_bf16(Ah, Nh, an, 0, 0, 0);
            ar = __builtin_amdgcn_mfma_f32_16x16x32_bf16(Ah, Rl, ar, 0, 0, 0);
            az = __builtin_amdgcn_mfma_f32_16x16x32_bf16(Ah, Zl, az, 0, 0, 0);
            an = __builtin_amdgcn_mfma_f32_16x16x32_bf16(Ah, Nl, an, 0, 0, 0);
            ar = __builtin_amdgcn_mfma_f32_16x16x32_bf16(Al, Rh, ar, 0, 0, 0);
            az = __builtin_amdgcn_mfma_f32_16x16x32_bf16(Al, Zh, az, 0, 0, 0);
            an = __builtin_amdgcn_mfma_f32_16x16x32_bf16(Al, Nh, an, 0, 0, 0);
        }

        #pragma unroll
        for (int q = 0; q < 4; ++q) {
            const int b = row0 + kg * 4 + q;   // C row = (l>>4)*4 + q
            const int v = (t < L) ? goal[(size_t)b * L + t] : EOS_TOK;
            const float* gi = gi_tok + (size_t)v * H3;
            float r = sigmoidf_(gi[j] + ar[q] + bhr);
            float z = sigmoidf_(gi[H + j] + az[q] + bhz);
            float nn = tanhf(gi[2 * H + j] + r * (an[q] + bhn));
            unsigned pw = __hip_atomic_load(pin + (size_t)b * H + j, __ATOMIC_RELAXED,
                                            __HIP_MEMORY_SCOPE_AGENT);
            float hp = bf2f((s16)(pw & 0xffff)) + bf2f((s16)(pw >> 16));
            float hn = (1.f - z) * nn + z * hp;
            __builtin_nontemporal_store(hn, h_out + (size_t)b * H + j);
            __hip_atomic_store(pout + (size_t)b * H + j, packsplit(hn),
                               __ATOMIC_RELAXED, __HIP_MEMORY_SCOPE_AGENT);
        }

        if (t < L) clusterbar(bar, c, (unsigned)(t + 2), tid);
    }
}

// ---------------- fused MLP via MFMA ----------------
__global__ __launch_bounds__(256, 1) void k_mlp_mfma(
        const float* __restrict__ states,
        const s16* __restrict__ w0h, const s16* __restrict__ w0l,
        const float* __restrict__ b0v,
        const s16* __restrict__ w1h, const s16* __restrict__ w1l,
        const float* __restrict__ b1v,
        const float* __restrict__ w2v, const float* __restrict__ b2v,
        float* __restrict__ out, int col0) {
    __shared__ float v1s[64 * 512];   // 128 KB
    __shared__ float red[4][64];
    const int tid = threadIdx.x;
    const int wid = tid >> 6;
    const int l = tid & 63;
    const int ln = l & 15;
    const int kg = l >> 4;
    const int r0 = blockIdx.x * 64;
    const int col = col0 + (r0 >> 8);
    const int b0 = r0 & 255;

    f32x4v acc[4][8];
    #pragma unroll
    for (int mf = 0; mf < 4; ++mf)
        #pragma unroll
        for (int nf = 0; nf < 8; ++nf) acc[mf][nf] = f32x4v{};

    // ---- GEMM1: v1 = relu(relu(h) @ w0.T + b0) ----
    for (int kc = 0; kc < H; kc += 32) {
        s16x8 Ah[4], Al[4];
        #pragma unroll
        for (int mf = 0; mf < 4; ++mf) {
            const float* ap = states + (size_t)(r0 + mf * 16 + ln) * H + kc + kg * 8;
            float4 x0 = *(const float4*)ap;
            float4 x1 = *(const float4*)(ap + 4);
            float y[8] = {fmaxf(x0.x,0.f), fmaxf(x0.y,0.f), fmaxf(x0.z,0.f), fmaxf(x0.w,0.f),
                          fmaxf(x1.x,0.f), fmaxf(x1.y,0.f), fmaxf(x1.z,0.f), fmaxf(x1.w,0.f)};
            #pragma unroll
            for (int i = 0; i < 8; ++i) {
                s16 hh = f2bf(y[i]);
                Ah[mf][i] = hh;
                Al[mf][i] = f2bf(y[i] - bf2f(hh));
            }
        }
        #pragma unroll
        for (int nf = 0; nf < 8; ++nf) {
            const int n = wid * 128 + nf * 16 + ln;
            s16x8 Bh = *(const s16x8*)(w0h + (size_t)n * H + kc + kg * 8);
            s16x8 Bl = *(const s16x8*)(w0l + (size_t)n * H + kc + kg * 8);
            #pragma unroll
            for (int mf = 0; mf < 4; ++mf) {
                acc[mf][nf] = __builtin_amdgcn_mfma_f32_16x16x32_bf16(Ah[mf], Bh, acc[mf][nf], 0, 0, 0);
                acc[mf][nf] = __builtin_amdgcn_mfma_f32_16x16x32_bf16(Ah[mf], Bl, acc[mf][nf], 0, 0, 0);
                acc[mf][nf] = __builtin_amdgcn_mfma_f32_16x16x32_bf16(Al[mf], Bh, acc[mf][nf], 0, 0, 0);
            }
        }
    }
    float bn[8];
    #pragma unroll
    for (int nf = 0; nf < 8; ++nf) bn[nf] = b0v[wid * 128 + nf * 16 + ln];
    #pragma unroll
    for (int mf = 0; mf < 4; ++mf)
        #pragma unroll
        for (int nf = 0; nf < 8; ++nf)
            #pragma unroll
            for (int q = 0; q < 4; ++q) {
                int m = mf * 16 + kg * 4 + q;
                int n = wid * 128 + nf * 16 + ln;
                v1s[m * 512 + (n ^ ((m & 7) << 2))] = fmaxf(acc[mf][nf][q] + bn[nf], 0.f);
            }
    __syncthreads();

    // ---- GEMM2: v2 = relu(v1 @ w1.T + b1); lik = v2 . w2 ----
    #pragma unroll
    for (int mf = 0; mf < 4; ++mf)
        #pragma unroll
        for (int nf = 0; nf < 8; ++nf) acc[mf][nf] = f32x4v{};
    for (int kc = 0; kc < H; kc += 32) {
        s16x8 Ah[4], Al[4];
        #pragma unroll
        for (int mf = 0; mf < 4; ++mf) {
            const int rr = mf * 16 + ln;
            const int c = (rr & 7) << 2;
            const int k0 = kc + kg * 8;
            float4 y0 = *(const float4*)(v1s + rr * 512 + (k0 ^ c));
            float4 y1 = *(const float4*)(v1s + rr * 512 + ((k0 + 4) ^ c));
            float y[8] = {y0.x, y0.y, y0.z, y0.w, y1.x, y1.y, y1.z, y1.w};
            #pragma unroll
            for (int i = 0; i < 8; ++i) {
                s16 hh = f2bf(y[i]);
                Ah[mf][i] = hh;
                Al[mf][i] = f2bf(y[i] - bf2f(hh));
            }
        }
        #pragma unroll
        for (int nf = 0; nf < 8; ++nf) {
            const int n = wid * 128 + nf * 16 + ln;
            s16x8 Bh = *(const s16x8*)(w1h + (size_t)n * H + kc + kg * 8);
            s16x8 Bl = *(const s16x8*)(w1l + (size_t)n * H + kc + kg * 8);
            #pragma unroll
            for (int mf = 0; mf < 4; ++mf) {
                acc[mf][nf] = __builtin_amdgcn_mfma_f32_16x16x32_bf16(Ah[mf], Bh, acc[mf][nf], 0, 0, 0);
                acc[mf][nf] = __builtin_amdgcn_mfma_f32_16x16x32_bf16(Ah[mf], Bl, acc[mf][nf], 0, 0, 0);
                acc[mf][nf] = __builtin_amdgcn_mfma_f32_16x16x32_bf16(Al[mf], Bh, acc[mf][nf], 0, 0, 0);
            }
        }
    }
    float b1n[8], w2n[8];
    #pragma unroll
    for (int nf = 0; nf < 8; ++nf) {
        int n = wid * 128 + nf * 16 + ln;
        b1n[nf] = b1v[n];
        w2n[nf] = w2v[n];
    }
    float psum[4][4];
    #pragma unroll
    for (int mf = 0; mf < 4; ++mf)
        #pragma unroll
        for (int q = 0; q < 4; ++q) {
            float s = 0.f;
            #pragma unroll
            for (int nf = 0; nf < 8; ++nf)
                s += fmaxf(acc[mf][nf][q] + b1n[nf], 0.f) * w2n[nf];
            psum[mf][q] = s;
        }
    #pragma unroll
    for (int mf = 0; mf < 4; ++mf)
        #pragma unroll
        for (int q = 0; q < 4; ++q) {
            float s = psum[mf][q];
            #pragma unroll
            for (int msk = 1; msk < 16; msk <<= 1)
                s += __shfl_xor(s, msk, 64);
            psum[mf][q] = s;
        }
    if (ln == 0) {
        #pragma unroll
        for (int mf = 0; mf < 4; ++mf)
            #pragma unroll
            for (int q = 0; q < 4; ++q)
                red[wid][mf * 16 + kg * 4 + q] = psum[mf][q];
    }
    __syncthreads();
    if (tid < 64) {
        float s = b2v[0] + red[0][tid] + red[1][tid] + red[2][tid] + red[3][tid];
        out[(size_t)(b0 + tid) * OUTC + col] = s;
    }
}

extern "C" void kernel_launch(void* const* d_in, const int* in_sizes, int n_in,
                              void* d_out, int out_size, void* d_ws, size_t ws_size,
                              hipStream_t stream) {
    (void)in_sizes; (void)n_in; (void)out_size; (void)ws_size;
    const int* stem = (const int*)d_in[0];
    const int* goal = (const int*)d_in[1];
    const float* stem_emb = (const float*)d_in[2];
    const float* token_emb = (const float*)d_in[3];
    const float* w_ih = (const float*)d_in[4];
    const float* w_hh = (const float*)d_in[5];
    const float* b_ih = (const float*)d_in[6];
    const float* b_hh = (const float*)d_in[7];
    const float* w0 = (const float*)d_in[8];
    const float* b0 = (const float*)d_in[9];
    const float* w1 = (const float*)d_in[10];
    const float* b1 = (const float*)d_in[11];
    const float* w2 = (const float*)d_in[12];
    const float* b2 = (const float*)d_in[13];
    float* out = (float*)d_out;

    char* p = (char*)d_ws;
    float* gi_tok = (float*)p;      p += (size_t)TOKV * H3 * 4;
    s16* whh_h = (s16*)p;           p += (size_t)H3 * H * 2;
    s16* whh_l = (s16*)p;           p += (size_t)H3 * H * 2;
    s16* w0h = (s16*)p;             p += (size_t)H * H * 2;
    s16* w0l = (s16*)p;             p += (size_t)H * H * 2;
    s16* w1h = (s16*)p;             p += (size_t)H * H * 2;
    s16* w1l = (s16*)p;             p += (size_t)H * H * 2;
    unsigned* spk0 = (unsigned*)p;  p += SLOT * 4;
    unsigned* spk1 = (unsigned*)p;  p += SLOT * 4;
    unsigned* bar = (unsigned*)p;   p += 4096;
    float* hs = (float*)p;          // 257 slots: [1..256]=post-step states, [0]=EOS final

    hipMemsetAsync(bar, 0, 4096, stream);

    // prep
    k_split<<<768, 256, 0, stream>>>(w_hh, whh_h, whh_l, H3 * H / 4);
    k_split<<<256, 256, 0, stream>>>(w0, w0h, w0l, H * H / 4);
    k_split<<<256, 256, 0, stream>>>(w1, w1h, w1l, H * H / 4);
    k_gi_tok<<<128, 256, 0, stream>>>(token_emb, w_ih, b_ih, gi_tok);

    // persistent clustered scan (h0 init + 256 GRU steps + EOS step)
    {
        const int* goal_a = goal;
        const int* stem_a = stem;
        const float* stem_emb_a = stem_emb;
        const s16* whh_h_a = whh_h;
        const s16* whh_l_a = whh_l;
        const float* b_hh_a = b_hh;
        const float* gi_tok_a = gi_tok;
        unsigned* spk0_a = spk0;
        unsigned* spk1_a = spk1;
        float* hs_a = hs;
        unsigned* bar_a = bar;
        void* kargs[] = {(void*)&goal_a, (void*)&stem_a, (void*)&stem_emb_a,
                         (void*)&whh_h_a, (void*)&whh_l_a, (void*)&b_hh_a,
                         (void*)&gi_tok_a, (void*)&spk0_a, (void*)&spk1_a,
                         (void*)&hs_a, (void*)&bar_a};
        hipLaunchCooperativeKernel((void*)k_scan, dim3(256), dim3(128),
                                   kargs, 0, stream);
    }

    // MLP: cols 1..256 from hs[1..256], col 0 (EOS) from hs[0]
    k_mlp_mfma<<<1024, 256, 0, stream>>>(hs + SLOT, w0h, w0l, b0,
                                         w1h, w1l, b1, w2, b2, out, 1);
    k_mlp_mfma<<<4, 256, 0, stream>>>(hs, w0h, w0l, b0,
                                      w1h, w1l, b1, w2, b2, out, 0);
}

// Round 7
// 2499.589 us; speedup vs baseline: 3.5981x; 1.3625x over previous
//
#include <hip/hip_runtime.h>
#include <math.h>

#define B 256
#define L 256
#define H 512
#define H3 1536
#define TOKV 128
#define EOS_TOK 1
#define OUTC 257
#define SLOT ((size_t)B * H)   // elements per h-state

typedef short s16;
typedef s16 s16x8 __attribute__((ext_vector_type(8)));
typedef s16 s16x4 __attribute__((ext_vector_type(4)));
typedef float f32x4v __attribute__((ext_vector_type(4)));
typedef unsigned long long u64;

__device__ __forceinline__ float sigmoidf_(float x) {
    return 1.0f / (1.0f + __expf(-x));
}

// fp32 -> bf16 bit pattern, round-to-nearest-even (same as (__bf16) cast)
__device__ __forceinline__ s16 f2bf(float x) {
    unsigned u = __builtin_bit_cast(unsigned, x);
    u += 0x7fffu + ((u >> 16) & 1u);
    return (s16)(u >> 16);
}
__device__ __forceinline__ float bf2f(s16 h) {
    return __builtin_bit_cast(float, ((unsigned)(unsigned short)h) << 16);
}
// pack hi(low16)|lo(high16) of a float's 2-term bf16 split
__device__ __forceinline__ unsigned packsplit(float x) {
    s16 hh = f2bf(x);
    s16 ll = f2bf(x - bf2f(hh));
    return (unsigned)(unsigned short)hh | ((unsigned)(unsigned short)ll << 16);
}

// ---------------- per-cluster barrier (monotonic, fully relaxed) ----------------
__device__ __forceinline__ void clusterbar(unsigned* bar, int c, unsigned n, int tid) {
    __syncthreads();
    if (tid == 0) {
        const unsigned tgt = 32u * n;
        unsigned* ctr = bar + c * 32;
        __hip_atomic_fetch_add(ctr, 1u, __ATOMIC_RELAXED, __HIP_MEMORY_SCOPE_AGENT);
        while (__hip_atomic_load(ctr, __ATOMIC_RELAXED, __HIP_MEMORY_SCOPE_AGENT) < tgt)
            __builtin_amdgcn_s_sleep(1);
    }
    __syncthreads();
}

// ---------------- prep: elementwise split of a fp32 weight array ----------------
__global__ __launch_bounds__(256) void k_split(const float* __restrict__ src,
                                               s16* __restrict__ hi,
                                               s16* __restrict__ lo, int n4) {
    int i = blockIdx.x * 256 + threadIdx.x;
    if (i >= n4) return;
    float4 x = ((const float4*)src)[i];
    float xs[4] = {x.x, x.y, x.z, x.w};
    s16x4 h, l;
    #pragma unroll
    for (int q = 0; q < 4; ++q) {
        s16 hh = f2bf(xs[q]);
        h[q] = hh;
        l[q] = f2bf(xs[q] - bf2f(hh));
    }
    *(s16x4*)(hi + (size_t)i * 4) = h;
    *(s16x4*)(lo + (size_t)i * 4) = l;
}

// ---------------- prep: gi_tok[v][j] = relu(token_emb[v]) . w_ih[j] + b_ih[j] (fp32) ----------------
__global__ __launch_bounds__(256) void k_gi_tok(
        const float* __restrict__ token_emb, const float* __restrict__ w_ih,
        const float* __restrict__ b_ih, float* __restrict__ gi_out) {
    __shared__ float wlds[96][132];
    __shared__ float elds[16][132];
    const int vi = blockIdx.x >> 4;
    const int ji = blockIdx.x & 15;
    const int v0 = vi << 4, j0 = ji * 96;
    const int tid = threadIdx.x;
    const int vl = tid & 7;
    const int jl = tid >> 3;
    float acc[2][3] = {{0.f, 0.f, 0.f}, {0.f, 0.f, 0.f}};
    for (int ck = 0; ck < 4; ++ck) {
        const int c0 = ck << 7;
        __syncthreads();
        for (int i = tid; i < 96 * 32; i += 256) {
            int row = i >> 5, c4 = i & 31;
            *(float4*)&wlds[row][c4 << 2] =
                *(const float4*)(w_ih + (size_t)(j0 + row) * H + c0 + (c4 << 2));
        }
        for (int i = tid; i < 16 * 32; i += 256) {
            int row = i >> 5, c4 = i & 31;
            float4 e = *(const float4*)(token_emb + (size_t)(v0 + row) * H + c0 + (c4 << 2));
            e.x = fmaxf(e.x, 0.f); e.y = fmaxf(e.y, 0.f);
            e.z = fmaxf(e.z, 0.f); e.w = fmaxf(e.w, 0.f);
            *(float4*)&elds[row][c4 << 2] = e;
        }
        __syncthreads();
        #pragma unroll 8
        for (int c = 0; c < 128; c += 4) {
            float4 wa = *(const float4*)&wlds[jl][c];
            float4 wb = *(const float4*)&wlds[32 + jl][c];
            float4 wc = *(const float4*)&wlds[64 + jl][c];
            float4 ea = *(const float4*)&elds[vl][c];
            float4 eb = *(const float4*)&elds[vl + 8][c];
            acc[0][0] += ea.x*wa.x + ea.y*wa.y + ea.z*wa.z + ea.w*wa.w;
            acc[0][1] += ea.x*wb.x + ea.y*wb.y + ea.z*wb.z + ea.w*wb.w;
            acc[0][2] += ea.x*wc.x + ea.y*wc.y + ea.z*wc.z + ea.w*wc.w;
            acc[1][0] += eb.x*wa.x + eb.y*wa.y + eb.z*wa.z + eb.w*wa.w;
            acc[1][1] += eb.x*wb.x + eb.y*wb.y + eb.z*wb.z + eb.w*wb.w;
            acc[1][2] += eb.x*wc.x + eb.y*wc.y + eb.z*wc.z + eb.w*wc.w;
        }
    }
    #pragma unroll
    for (int p = 0; p < 2; ++p) {
        int v = v0 + vl + (p << 3);
        #pragma unroll
        for (int s = 0; s < 3; ++s) {
            int j = j0 + (s << 5) + jl;
            gi_out[(size_t)v * H3 + j] = acc[p][s] + b_ih[j];
        }
    }
}

// ---------------- persistent GRU scan, clustered (cooperative, 256 WGs x 128 thr) ----------------
// WG wg: cluster c = wg&7 (rows c*32..+32), j-slice jt = wg>>3 (cols jt*16..+16).
// Weights in LDS fragment-major (conflict-free). h exchange via packed u32
// (bf16 hi|lo<<16) relaxed agent atomics. A-loads for the whole K are
// batch-issued into registers (one IF latency exposed, not 16). hprev is
// carried in registers (same lane computes the same (b,j) every step).
__global__ __launch_bounds__(128, 1) void k_scan(
        const int* __restrict__ goal, const int* __restrict__ stem,
        const float* __restrict__ stem_emb,
        const s16* __restrict__ w_hi, const s16* __restrict__ w_lo,
        const float* __restrict__ b_hh, const float* __restrict__ gi_tok,
        unsigned* __restrict__ spk0, unsigned* __restrict__ spk1,
        float* __restrict__ hs, unsigned* bar) {
    __shared__ s16 wlds[96 * 512];   // 96 KB, viewed as [6][16][64][8]
    const int tid = threadIdx.x;
    const int wg = blockIdx.x;
    const int c = wg & 7;
    const int jt = wg >> 3;
    const int w = tid >> 6;
    const int l = tid & 63;
    const int ln = l & 15;
    const int kg = l >> 4;
    const int row0 = c * 32 + w * 16;   // this wave's 16 batch rows
    const int j = jt * 16 + ln;

    // one-time: stage weight slice into LDS, fragment-major.
    for (int i = tid; i < 6144; i += 128) {
        int lane = i & 63;
        int chunk = i >> 6;           // 0..95 = g2*16 + kcIdx
        int g2 = chunk >> 4;          // gate*2 + hl
        int kcIdx = chunk & 15;
        int gate = g2 >> 1, hl = g2 & 1;
        int lnn = lane & 15, kgg = lane >> 4;
        const s16* src = (hl ? w_lo : w_hi) +
                         ((size_t)(gate * H + jt * 16 + lnn)) * H + kcIdx * 32 + kgg * 8;
        *(s16x8*)(wlds + (size_t)i * 8) = *(const s16x8*)src;
    }
    // one-time: h0 split (packed) for this cluster's rows; WG jt inits row c*32+jt
    {
        int b = c * 32 + jt;
        int c4 = tid;                 // 0..127 float4s
        float4 v = ((const float4*)(stem_emb + (size_t)stem[b] * H))[c4];
        float xs[4] = {v.x, v.y, v.z, v.w};
        #pragma unroll
        for (int q = 0; q < 4; ++q)
            __hip_atomic_store(spk0 + (size_t)b * H + c4 * 4 + q, packsplit(xs[q]),
                               __ATOMIC_RELAXED, __HIP_MEMORY_SCOPE_AGENT);
    }
    // hprev in registers: exact h0 at this lane's (b, j) positions
    float hprev[4];
    #pragma unroll
    for (int q = 0; q < 4; ++q) {
        int b = row0 + kg * 4 + q;
        hprev[q] = stem_emb[(size_t)stem[b] * H + j];
    }
    clusterbar(bar, c, 1u, tid);

    const float bhr = b_hh[j], bhz = b_hh[H + j], bhn = b_hh[2 * H + j];

    for (int t = 0; t <= L; ++t) {
        unsigned* pin = (t & 1) ? spk1 : spk0;
        unsigned* pout = (t & 1) ? spk0 : spk1;
        float* h_out = (t < L) ? (hs + (size_t)(t + 1) * SLOT) : hs;  // EOS -> slot 0

        const u64* ap = (const u64*)pin + (size_t)(row0 + ln) * (H / 2) + kg * 4;

        // batch-issue ALL A-loads for this step (64 x 8B sc1 loads in flight)
        u64 av[64];
        #pragma unroll
        for (int kc = 0; kc < 16; ++kc)
            #pragma unroll
            for (int ii = 0; ii < 4; ++ii)
                av[kc * 4 + ii] = __hip_atomic_load(ap + kc * 16 + ii,
                                                    __ATOMIC_RELAXED,
                                                    __HIP_MEMORY_SCOPE_AGENT);

        // token + gi prefetch (normal cached loads; complete under MFMA phase)
        int bq[4];
        float g0[4], g1[4], g2v[4];
        #pragma unroll
        for (int q = 0; q < 4; ++q) {
            bq[q] = row0 + kg * 4 + q;
            int v = (t < L) ? goal[(size_t)bq[q] * L + t] : EOS_TOK;
            const float* gi = gi_tok + (size_t)v * H3;
            g0[q] = gi[j];
            g1[q] = gi[H + j];
            g2v[q] = gi[2 * H + j];
        }

        f32x4v ar{}, az{}, an{};
        #pragma unroll
        for (int kcIdx = 0; kcIdx < 16; ++kcIdx) {
            s16x8 Ah, Al;
            #pragma unroll
            for (int i = 0; i < 4; ++i) {
                u64 wv = av[kcIdx * 4 + i];
                unsigned lo32 = (unsigned)wv, hi32 = (unsigned)(wv >> 32);
                Ah[2 * i]     = (s16)(lo32 & 0xffff);
                Al[2 * i]     = (s16)(lo32 >> 16);
                Ah[2 * i + 1] = (s16)(hi32 & 0xffff);
                Al[2 * i + 1] = (s16)(hi32 >> 16);
            }
            const s16* bb = wlds + ((size_t)(kcIdx * 64 + l)) * 8;
            s16x8 Rh = *(const s16x8*)(bb);
            s16x8 Rl = *(const s16x8*)(bb + 8192);
            s16x8 Zh = *(const s16x8*)(bb + 16384);
            s16x8 Zl = *(const s16x8*)(bb + 24576);
            s16x8 Nh = *(const s16x8*)(bb + 32768);
            s16x8 Nl = *(const s16x8*)(bb + 40960);
            ar = __builtin_amdgcn_mfma_f32_16x16x32_bf16(Ah, Rh, ar, 0, 0, 0);
            az = __builtin_amdgcn_mfma_f32_16x16x32_bf16(Ah, Zh, az, 0, 0, 0);
            an = __builtin_amdgcn_mfma_f32_16x16x32_bf16(Ah, Nh, an, 0, 0, 0);
            ar = __builtin_amdgcn_mfma_f32_16x16x32_bf16(Ah, Rl, ar, 0, 0, 0);
            az = __builtin_amdgcn_mfma_f32_16x16x32_bf16(Ah, Zl, az, 0, 0, 0);
            an = __builtin_amdgcn_mfma_f32_16x16x32_bf16(Ah, Nl, an, 0, 0, 0);
            ar = __builtin_amdgcn_mfma_f32_16x16x32_bf16(Al, Rh, ar, 0, 0, 0);
            az = __builtin_amdgcn_mfma_f32_16x16x32_bf16(Al, Zh, az, 0, 0, 0);
            an = __builtin_amdgcn_mfma_f32_16x16x32_bf16(Al, Nh, an, 0, 0, 0);
        }

        #pragma unroll
        for (int q = 0; q < 4; ++q) {
            float r = sigmoidf_(g0[q] + ar[q] + bhr);
            float z = sigmoidf_(g1[q] + az[q] + bhz);
            float x = g2v[q] + r * (an[q] + bhn);
            float e = __expf(-2.f * x);
            float nn = (1.f - e) / (1.f + e);         // tanh(x)
            float hn = (1.f - z) * nn + z * hprev[q];
            hprev[q] = hn;
            __builtin_nontemporal_store(hn, h_out + (size_t)bq[q] * H + j);
            __hip_atomic_store(pout + (size_t)bq[q] * H + j, packsplit(hn),
                               __ATOMIC_RELAXED, __HIP_MEMORY_SCOPE_AGENT);
        }

        if (t < L) clusterbar(bar, c, (unsigned)(t + 2), tid);
    }
}

// ---------------- fused MLP via MFMA ----------------
__global__ __launch_bounds__(256, 1) void k_mlp_mfma(
        const float* __restrict__ states,
        const s16* __restrict__ w0h, const s16* __restrict__ w0l,
        const float* __restrict__ b0v,
        const s16* __restrict__ w1h, const s16* __restrict__ w1l,
        const float* __restrict__ b1v,
        const float* __restrict__ w2v, const float* __restrict__ b2v,
        float* __restrict__ out, int col0) {
    __shared__ float v1s[64 * 512];   // 128 KB
    __shared__ float red[4][64];
    const int tid = threadIdx.x;
    const int wid = tid >> 6;
    const int l = tid & 63;
    const int ln = l & 15;
    const int kg = l >> 4;
    const int r0 = blockIdx.x * 64;
    const int col = col0 + (r0 >> 8);
    const int b0 = r0 & 255;

    f32x4v acc[4][8];
    #pragma unroll
    for (int mf = 0; mf < 4; ++mf)
        #pragma unroll
        for (int nf = 0; nf < 8; ++nf) acc[mf][nf] = f32x4v{};

    // ---- GEMM1: v1 = relu(relu(h) @ w0.T + b0) ----
    for (int kc = 0; kc < H; kc += 32) {
        s16x8 Ah[4], Al[4];
        #pragma unroll
        for (int mf = 0; mf < 4; ++mf) {
            const float* ap = states + (size_t)(r0 + mf * 16 + ln) * H + kc + kg * 8;
            float4 x0 = *(const float4*)ap;
            float4 x1 = *(const float4*)(ap + 4);
            float y[8] = {fmaxf(x0.x,0.f), fmaxf(x0.y,0.f), fmaxf(x0.z,0.f), fmaxf(x0.w,0.f),
                          fmaxf(x1.x,0.f), fmaxf(x1.y,0.f), fmaxf(x1.z,0.f), fmaxf(x1.w,0.f)};
            #pragma unroll
            for (int i = 0; i < 8; ++i) {
                s16 hh = f2bf(y[i]);
                Ah[mf][i] = hh;
                Al[mf][i] = f2bf(y[i] - bf2f(hh));
            }
        }
        #pragma unroll
        for (int nf = 0; nf < 8; ++nf) {
            const int n = wid * 128 + nf * 16 + ln;
            s16x8 Bh = *(const s16x8*)(w0h + (size_t)n * H + kc + kg * 8);
            s16x8 Bl = *(const s16x8*)(w0l + (size_t)n * H + kc + kg * 8);
            #pragma unroll
            for (int mf = 0; mf < 4; ++mf) {
                acc[mf][nf] = __builtin_amdgcn_mfma_f32_16x16x32_bf16(Ah[mf], Bh, acc[mf][nf], 0, 0, 0);
                acc[mf][nf] = __builtin_amdgcn_mfma_f32_16x16x32_bf16(Ah[mf], Bl, acc[mf][nf], 0, 0, 0);
                acc[mf][nf] = __builtin_amdgcn_mfma_f32_16x16x32_bf16(Al[mf], Bh, acc[mf][nf], 0, 0, 0);
            }
        }
    }
    float bn[8];
    #pragma unroll
    for (int nf = 0; nf < 8; ++nf) bn[nf] = b0v[wid * 128 + nf * 16 + ln];
    #pragma unroll
    for (int mf = 0; mf < 4; ++mf)
        #pragma unroll
        for (int nf = 0; nf < 8; ++nf)
            #pragma unroll
            for (int q = 0; q < 4; ++q) {
                int m = mf * 16 + kg * 4 + q;
                int n = wid * 128 + nf * 16 + ln;
                v1s[m * 512 + (n ^ ((m & 7) << 2))] = fmaxf(acc[mf][nf][q] + bn[nf], 0.f);
            }
    __syncthreads();

    // ---- GEMM2: v2 = relu(v1 @ w1.T + b1); lik = v2 . w2 ----
    #pragma unroll
    for (int mf = 0; mf < 4; ++mf)
        #pragma unroll
        for (int nf = 0; nf < 8; ++nf) acc[mf][nf] = f32x4v{};
    for (int kc = 0; kc < H; kc += 32) {
        s16x8 Ah[4], Al[4];
        #pragma unroll
        for (int mf = 0; mf < 4; ++mf) {
            const int rr = mf * 16 + ln;
            const int c = (rr & 7) << 2;
            const int k0 = kc + kg * 8;
            float4 y0 = *(const float4*)(v1s + rr * 512 + (k0 ^ c));
            float4 y1 = *(const float4*)(v1s + rr * 512 + ((k0 + 4) ^ c));
            float y[8] = {y0.x, y0.y, y0.z, y0.w, y1.x, y1.y, y1.z, y1.w};
            #pragma unroll
            for (int i = 0; i < 8; ++i) {
                s16 hh = f2bf(y[i]);
                Ah[mf][i] = hh;
                Al[mf][i] = f2bf(y[i] - bf2f(hh));
            }
        }
        #pragma unroll
        for (int nf = 0; nf < 8; ++nf) {
            const int n = wid * 128 + nf * 16 + ln;
            s16x8 Bh = *(const s16x8*)(w1h + (size_t)n * H + kc + kg * 8);
            s16x8 Bl = *(const s16x8*)(w1l + (size_t)n * H + kc + kg * 8);
            #pragma unroll
            for (int mf = 0; mf < 4; ++mf) {
                acc[mf][nf] = __builtin_amdgcn_mfma_f32_16x16x32_bf16(Ah[mf], Bh, acc[mf][nf], 0, 0, 0);
                acc[mf][nf] = __builtin_amdgcn_mfma_f32_16x16x32_bf16(Ah[mf], Bl, acc[mf][nf], 0, 0, 0);
                acc[mf][nf] = __builtin_amdgcn_mfma_f32_16x16x32_bf16(Al[mf], Bh, acc[mf][nf], 0, 0, 0);
            }
        }
    }
    float b1n[8], w2n[8];
    #pragma unroll
    for (int nf = 0; nf < 8; ++nf) {
        int n = wid * 128 + nf * 16 + ln;
        b1n[nf] = b1v[n];
        w2n[nf] = w2v[n];
    }
    float psum[4][4];
    #pragma unroll
    for (int mf = 0; mf < 4; ++mf)
        #pragma unroll
        for (int q = 0; q < 4; ++q) {
            float s = 0.f;
            #pragma unroll
            for (int nf = 0; nf < 8; ++nf)
                s += fmaxf(acc[mf][nf][q] + b1n[nf], 0.f) * w2n[nf];
            psum[mf][q] = s;
        }
    #pragma unroll
    for (int mf = 0; mf < 4; ++mf)
        #pragma unroll
        for (int q = 0; q < 4; ++q) {
            float s = psum[mf][q];
            #pragma unroll
            for (int msk = 1; msk < 16; msk <<= 1)
                s += __shfl_xor(s, msk, 64);
            psum[mf][q] = s;
        }
    if (ln == 0) {
        #pragma unroll
        for (int mf = 0; mf < 4; ++mf)
            #pragma unroll
            for (int q = 0; q < 4; ++q)
                red[wid][mf * 16 + kg * 4 + q] = psum[mf][q];
    }
    __syncthreads();
    if (tid < 64) {
        float s = b2v[0] + red[0][tid] + red[1][tid] + red[2][tid] + red[3][tid];
        out[(size_t)(b0 + tid) * OUTC + col] = s;
    }
}

extern "C" void kernel_launch(void* const* d_in, const int* in_sizes, int n_in,
                              void* d_out, int out_size, void* d_ws, size_t ws_size,
                              hipStream_t stream) {
    (void)in_sizes; (void)n_in; (void)out_size; (void)ws_size;
    const int* stem = (const int*)d_in[0];
    const int* goal = (const int*)d_in[1];
    const float* stem_emb = (const float*)d_in[2];
    const float* token_emb = (const float*)d_in[3];
    const float* w_ih = (const float*)d_in[4];
    const float* w_hh = (const float*)d_in[5];
    const float* b_ih = (const float*)d_in[6];
    const float* b_hh = (const float*)d_in[7];
    const float* w0 = (const float*)d_in[8];
    const float* b0 = (const float*)d_in[9];
    const float* w1 = (const float*)d_in[10];
    const float* b1 = (const float*)d_in[11];
    const float* w2 = (const float*)d_in[12];
    const float* b2 = (const float*)d_in[13];
    float* out = (float*)d_out;

    char* p = (char*)d_ws;
    float* gi_tok = (float*)p;      p += (size_t)TOKV * H3 * 4;
    s16* whh_h = (s16*)p;           p += (size_t)H3 * H * 2;
    s16* whh_l = (s16*)p;           p += (size_t)H3 * H * 2;
    s16* w0h = (s16*)p;             p += (size_t)H * H * 2;
    s16* w0l = (s16*)p;             p += (size_t)H * H * 2;
    s16* w1h = (s16*)p;             p += (size_t)H * H * 2;
    s16* w1l = (s16*)p;             p += (size_t)H * H * 2;
    unsigned* spk0 = (unsigned*)p;  p += SLOT * 4;
    unsigned* spk1 = (unsigned*)p;  p += SLOT * 4;
    unsigned* bar = (unsigned*)p;   p += 4096;
    float* hs = (float*)p;          // 257 slots: [1..256]=post-step states, [0]=EOS final

    hipMemsetAsync(bar, 0, 4096, stream);

    // prep
    k_split<<<768, 256, 0, stream>>>(w_hh, whh_h, whh_l, H3 * H / 4);
    k_split<<<256, 256, 0, stream>>>(w0, w0h, w0l, H * H / 4);
    k_split<<<256, 256, 0, stream>>>(w1, w1h, w1l, H * H / 4);
    k_gi_tok<<<128, 256, 0, stream>>>(token_emb, w_ih, b_ih, gi_tok);

    // persistent clustered scan (h0 init + 256 GRU steps + EOS step)
    {
        const int* goal_a = goal;
        const int* stem_a = stem;
        const float* stem_emb_a = stem_emb;
        const s16* whh_h_a = whh_h;
        const s16* whh_l_a = whh_l;
        const float* b_hh_a = b_hh;
        const float* gi_tok_a = gi_tok;
        unsigned* spk0_a = spk0;
        unsigned* spk1_a = spk1;
        float* hs_a = hs;
        unsigned* bar_a = bar;
        void* kargs[] = {(void*)&goal_a, (void*)&stem_a, (void*)&stem_emb_a,
                         (void*)&whh_h_a, (void*)&whh_l_a, (void*)&b_hh_a,
                         (void*)&gi_tok_a, (void*)&spk0_a, (void*)&spk1_a,
                         (void*)&hs_a, (void*)&bar_a};
        hipLaunchCooperativeKernel((void*)k_scan, dim3(256), dim3(128),
                                   kargs, 0, stream);
    }

    // MLP: cols 1..256 from hs[1..256], col 0 (EOS) from hs[0]
    k_mlp_mfma<<<1024, 256, 0, stream>>>(hs + SLOT, w0h, w0l, b0,
                                         w1h, w1l, b1, w2, b2, out, 1);
    k_mlp_mfma<<<4, 256, 0, stream>>>(hs, w0h, w0l, b0,
                                      w1h, w1l, b1, w2, b2, out, 0);
}